// Round 18
// baseline (269.698 us; speedup 1.0000x reference)
//
#include <hip/hip_runtime.h>
#include <cmath>

#define NB   16
#define CINC 256
#define DPC  512
#define COUTC 256
#define HWS  4096
#define EPSF 1.1920928955078125e-07f
#define BN_EPS 1e-5f
#define EXP_CLAMP 88.722835f
#define TS 76   // pooldisp tmp f32 stride
#define PS2 66  // pooldisp pl ushort stride

typedef unsigned int uint32;
typedef unsigned short ushort;
typedef __bf16 bf16x8 __attribute__((ext_vector_type(8)));
typedef float f32x4 __attribute__((ext_vector_type(4)));
typedef unsigned short ushort8 __attribute__((ext_vector_type(8)));

__device__ inline ushort f2bf(float f) {          // native RNE cvt
    __bf16 h = (__bf16)f;
    return __builtin_bit_cast(ushort, h);
}
__device__ inline float bf2f(ushort u) {
    return __builtin_bit_cast(float, (uint32)u << 16);
}
__device__ inline float softplus_fast(float v) {
    return fmaxf(v, 0.f) + __logf(1.f + __expf(-fabsf(v)));
}
__device__ __forceinline__ void gload16(const void* g, void* l) {
    __builtin_amdgcn_global_load_lds(
        (__attribute__((address_space(1))) void*)g,
        (__attribute__((address_space(3))) void*)l, 16, 0, 0);
}
// raw barrier fenced against ALL instruction motion
__device__ __forceinline__ void hard_barrier() {
    __builtin_amdgcn_sched_barrier(0);
    __builtin_amdgcn_s_barrier();
    __builtin_amdgcn_sched_barrier(0);
}

// ---------------------------------------------------------------------------
// MFMA bf16 GEMM, 256(M)x128(N) tile, 4 waves of 128x64 = (8,4) frag grid.
// 2-slab counted-vmcnt pipeline: vmcnt(6) waits current slab; refill after
// the 2nd fenced barrier.  Conflict-free LDS via source-side slot
// permutation (slot ^= (row>>1)&3).
// SWZ: XCD-chunked bijective block swizzle (1-D grid of 2048): the 4 blocks
// sharing a B-tile (same hw0,b; o-tile fastest) run consecutively on the
// SAME XCD -> B-tile L2-hits instead of 4x L3 pulls.
// out[b][o][hw] = bias[o] + sum_k A[o][k] * BT[b][hw][k]
// DUALBIAS: bias split at o=512.  PARTIALS: add f32 skip, write bf16 t, and
// emit per-channel (sum, sumsq) partials.
// ---------------------------------------------------------------------------
template<int OTOT, int KTOT, bool DUALBIAS, bool PARTIALS, bool SWZ>
__global__ __launch_bounds__(256) void mfma_gemm_k(
    const ushort* __restrict__ A, const ushort* __restrict__ BT,
    const float* __restrict__ bias1, const float* __restrict__ bias2,
    const float* __restrict__ skip, ushort* __restrict__ outp,
    float* __restrict__ part_s, float* __restrict__ part_s2) {
    int hw_t, o_t, b;
    if constexpr (SWZ) {
        // grid = 2048 linear blocks; bijective: logical = (raw&7)*256 + raw>>3
        int raw = blockIdx.x;
        int logical = (raw & 7) * 256 + (raw >> 3);
        o_t  = logical & 3;           // o-tile fastest: 4 sharers of one B-tile
        hw_t = (logical >> 2) & 31;
        b    = logical >> 7;
    } else {
        hw_t = blockIdx.x; o_t = blockIdx.y; b = blockIdx.z;
    }
    const int hw0 = hw_t * 128;
    const int o0  = o_t * 256;
    __shared__ ushort As[2][256 * 32];   // 32 KB
    __shared__ ushort Bs[2][128 * 32];   // 16 KB
    const int tid  = threadIdx.x;
    const int lane = tid & 63;
    const int w    = tid >> 6;
    const int wm0  = (w >> 1) * 128;     // o-half
    const int wn0  = (w & 1) * 64;       // hw-half

    f32x4 acc[8][4] = {};

    const ushort* Ab = A + (size_t)o0 * KTOT;
    const ushort* Bb = BT + ((size_t)b * HWS + hw0) * KTOT;
    const int rsub  = lane >> 2;
    const int ksubp = ((lane & 3) ^ ((lane >> 3) & 3)) * 8;

    auto stage = [&](int buf, int k0) {   // 6 global_load_lds per thread
#pragma unroll
        for (int i = 0; i < 4; ++i) {     // A: wave w covers rows w*64 .. +63
            const int row = w * 64 + i * 16 + rsub;
            gload16(Ab + (size_t)row * KTOT + k0 + ksubp, &As[buf][(w * 64 + i * 16) * 32]);
        }
#pragma unroll
        for (int i = 0; i < 2; ++i) {     // B: wave w covers rows w*32 .. +31
            const int row = w * 32 + i * 16 + rsub;
            gload16(Bb + (size_t)row * KTOT + k0 + ksubp, &Bs[buf][(w * 32 + i * 16) * 32]);
        }
    };

    constexpr int NSTEP = KTOT / 32;
    stage(0, 0);
    stage(1, 32);
    int cur = 0;
    for (int step = 0; step < NSTEP; ++step) {
        // wait for current slab only; next slab's 6 loads stay in flight
        if (step == NSTEP - 1) asm volatile("s_waitcnt vmcnt(0)" ::: "memory");
        else                   asm volatile("s_waitcnt vmcnt(6)" ::: "memory");
        hard_barrier();                      // all waves' current slab landed
        bf16x8 af[8], bfr[4];
#pragma unroll
        for (int mi = 0; mi < 8; ++mi) {
            int row = wm0 + mi * 16 + (lane & 15);
            int sl = (lane >> 4) ^ ((row >> 1) & 3);
            af[mi] = *reinterpret_cast<const bf16x8*>(&As[cur][row * 32 + sl * 8]);
        }
#pragma unroll
        for (int ni = 0; ni < 4; ++ni) {
            int row = wn0 + ni * 16 + (lane & 15);
            int sl = (lane >> 4) ^ ((row >> 1) & 3);
            bfr[ni] = *reinterpret_cast<const bf16x8*>(&Bs[cur][row * 32 + sl * 8]);
        }
#pragma unroll
        for (int mi = 0; mi < 8; ++mi)
#pragma unroll
            for (int ni = 0; ni < 4; ++ni)
                acc[mi][ni] = __builtin_amdgcn_mfma_f32_16x16x32_bf16(
                    af[mi], bfr[ni], acc[mi][ni], 0, 0, 0);
        hard_barrier();                      // all waves done READING cur
        if (step + 2 < NSTEP) stage(cur, (step + 2) * 32);   // refill cur
        cur ^= 1;
    }

    // reuse dead staging LDS for partial-sum exchange
    float* pS  = reinterpret_cast<float*>(&As[0][0]);   // [2][256]
    float* pS2 = pS + 512;
    if constexpr (PARTIALS) __syncthreads();   // staging drained (vmcnt 0)

    // D frag: col = lane&15 (hw), row = (lane>>4)*4 + r (o).
#pragma unroll
    for (int mi = 0; mi < 8; ++mi) {
#pragma unroll
        for (int r = 0; r < 4; ++r) {
            int chL = wm0 + mi * 16 + ((lane >> 4) << 2) + r;
            int o = o0 + chL;
            float bi;
            if constexpr (DUALBIAS) bi = (o < 512) ? bias1[o] : bias2[o - 512];
            else bi = bias1[o];
            size_t base = ((size_t)b * OTOT + o) * HWS + hw0 + wn0 + (lane & 15);
            float s1 = 0.f, s2 = 0.f;
#pragma unroll
            for (int ni = 0; ni < 4; ++ni) {
                float v = acc[mi][ni][r] + bi;
                if constexpr (PARTIALS) v += skip[base + ni * 16];
                ushort tb = f2bf(v);
                outp[base + ni * 16] = tb;
                if constexpr (PARTIALS) {
                    float vf = bf2f(tb);
                    s1 += vf; s2 += vf * vf;
                }
            }
            if constexpr (PARTIALS) {
#pragma unroll
                for (int off = 1; off <= 8; off <<= 1) {
                    s1 += __shfl_xor(s1, off, 64);
                    s2 += __shfl_xor(s2, off, 64);
                }
                if ((lane & 15) == 0) {
                    pS[(w & 1) * 256 + chL]  = s1;
                    pS2[(w & 1) * 256 + chL] = s2;
                }
            }
        }
    }
    if constexpr (PARTIALS) {
        __syncthreads();
        if (tid < 256) {
            int k = hw_t * NB + b;   // 0..511
            float S  = pS[tid]  + pS[256 + tid];
            float S2 = pS2[tid] + pS2[256 + tid];
            part_s[(size_t)(o0 + tid) * 512 + k]  = S;
            part_s2[(size_t)(o0 + tid) * 512 + k] = S2;
        }
    }
}

// ---------------------------------------------------------------------------
// x [B][256][HW] f32  ->  xT [B][HW][256] bf16
// ---------------------------------------------------------------------------
__global__ __launch_bounds__(256) void castT_k(const float* __restrict__ x,
                                               ushort* __restrict__ xT) {
    const int b = blockIdx.z, c0 = blockIdx.y * 64, hw0 = blockIdx.x * 64;
    __shared__ float tile[64][65];
    const int tid = threadIdx.x;
#pragma unroll
    for (int r = 0; r < 16; ++r) {
        int cl = r * 4 + (tid >> 6), hwl = tid & 63;
        tile[cl][hwl] = x[((size_t)b * CINC + c0 + cl) * HWS + hw0 + hwl];
    }
    __syncthreads();
#pragma unroll
    for (int r = 0; r < 16; ++r) {
        int hwl = r * 4 + (tid >> 6), cl = tid & 63;
        xT[((size_t)b * HWS + hw0 + hwl) * CINC + c0 + cl] = f2bf(tile[cl][hwl]);
    }
}

// generic f32 -> bf16 cast
__global__ __launch_bounds__(256) void cast_k(const float* __restrict__ in,
                                              ushort* __restrict__ out, int n) {
    int i = (blockIdx.x * 256 + threadIdx.x) * 4;
    if (i < n) {
        float4 v = *reinterpret_cast<const float4*>(in + i);
        out[i + 0] = f2bf(v.x); out[i + 1] = f2bf(v.y);
        out[i + 2] = f2bf(v.z); out[i + 3] = f2bf(v.w);
    }
}

// ---------------------------------------------------------------------------
// FUSED dynamic_pool + displace v4: 512 threads, exp+row-pass fused -> tmp
// f32; col-pass+log -> pl bf16 (stride 66); displace with 9-tap reuse.
// IN PLACE on plane (b,c) of dpout[b][1024][hw], c < 512.
// ---------------------------------------------------------------------------
__global__ __launch_bounds__(512, 8) void pooldisp_k(ushort* __restrict__ dp,
                                                     const float* __restrict__ sigma,
                                                     const float* __restrict__ offsets) {
    const int bc = blockIdx.x;
    const int b = bc >> 9, c = bc & 511;
    __shared__ float  tmp[68 * TS];
    __shared__ ushort pl[64 * PS2];
    const int tid = threadIdx.x;
    ushort* ip = dp + ((size_t)b * 1024 + c) * HWS;

    float s = sigma[c];
    float inv = 0.5f / (s * s + EPSF);
    float g0 = __expf(-4.f * inv), g1 = __expf(-1.f * inv);
    float gs = g0 + g1 + 1.f + g1 + g0;
    float rnorm = 1.f / (gs * gs);

    {
        int r4 = tid >> 7, col = tid & 127;
        if (col < TS) {
            int row = (r4 < 2) ? r4 : 64 + r4;   // 0,1,66,67
            tmp[row * TS + col] = 0.f;
        }
    }
    {
        int hr = tid >> 3, w0 = (tid & 7) * 8;
        const ushort* rp = ip + hr * 64 + w0;
        ushort8 mv = *reinterpret_cast<const ushort8*>(rp);
        float e[12];
        e[0] = (w0 > 0) ? __expf(fminf(bf2f(rp[-2]), EXP_CLAMP)) : 0.f;
        e[1] = (w0 > 0) ? __expf(fminf(bf2f(rp[-1]), EXP_CLAMP)) : 0.f;
#pragma unroll
        for (int q = 0; q < 8; ++q)
            e[2 + q] = __expf(fminf(bf2f(mv[q]), EXP_CLAMP));
        e[10] = (w0 < 56) ? __expf(fminf(bf2f(rp[8]), EXP_CLAMP)) : 0.f;
        e[11] = (w0 < 56) ? __expf(fminf(bf2f(rp[9]), EXP_CLAMP)) : 0.f;
        f32x4 o0, o1;
#pragma unroll
        for (int j = 0; j < 4; ++j) {
            o0[j] = g0 * (e[j] + e[j + 4]) + g1 * (e[j + 1] + e[j + 3]) + e[j + 2];
            o1[j] = g0 * (e[j + 4] + e[j + 8]) + g1 * (e[j + 5] + e[j + 7]) + e[j + 6];
        }
        *reinterpret_cast<f32x4*>(&tmp[(hr + 2) * TS + w0]) = o0;
        *reinterpret_cast<f32x4*>(&tmp[(hr + 2) * TS + w0 + 4]) = o1;
    }
    __syncthreads();

#pragma unroll
    for (int t = 0; t < 2; ++t) {
        int task = tid + t * 512;
        int h = task >> 4, wq = (task & 15) * 4;
        f32x4 t0 = *reinterpret_cast<const f32x4*>(&tmp[(h + 0) * TS + wq]);
        f32x4 t1 = *reinterpret_cast<const f32x4*>(&tmp[(h + 1) * TS + wq]);
        f32x4 t2 = *reinterpret_cast<const f32x4*>(&tmp[(h + 2) * TS + wq]);
        f32x4 t3 = *reinterpret_cast<const f32x4*>(&tmp[(h + 3) * TS + wq]);
        f32x4 t4 = *reinterpret_cast<const f32x4*>(&tmp[(h + 4) * TS + wq]);
        ushort o[4];
#pragma unroll
        for (int j = 0; j < 4; ++j) {
            float v = g0 * (t0[j] + t4[j]) + g1 * (t1[j] + t3[j]) + t2[j];
            o[j] = f2bf(__logf(v * rnorm + EPSF));
        }
        *reinterpret_cast<uint32*>(&pl[h * PS2 + wq]) =
            (uint32)o[0] | ((uint32)o[1] << 16);
        *reinterpret_cast<uint32*>(&pl[h * PS2 + wq + 2]) =
            (uint32)o[2] | ((uint32)o[3] << 16);
    }
    __syncthreads();

    {
        int oi = c >> 3;
        float dy = offsets[oi * 2 + 0];
        float dx = offsets[oi * 2 + 1];
        float y0f = floorf(dy), x0f = floorf(dx);
        float fy = dy - y0f, fx = dx - x0f;
        int y0 = (int)y0f, x0 = (int)x0f;
        float w00 = (1.f - fy) * (1.f - fx), w01 = (1.f - fy) * fx;
        float w10 = fy * (1.f - fx),         w11 = fy * fx;
        int h = tid >> 3, w = (tid & 7) * 8;
        int ry0 = h + y0, ry1 = ry0 + 1;
        bool my0 = (ry0 >= 0) & (ry0 < 64);
        bool my1 = (ry1 >= 0) & (ry1 < 64);
        float e0[9], e1[9];
#pragma unroll
        for (int j = 0; j < 9; ++j) {
            int col = w + x0 + j;
            bool mx = (col >= 0) & (col < 64);
            e0[j] = (my0 & mx) ? bf2f(pl[ry0 * PS2 + col]) : 0.f;
            e1[j] = (my1 & mx) ? bf2f(pl[ry1 * PS2 + col]) : 0.f;
        }
        ushort8 ov;
#pragma unroll
        for (int q = 0; q < 8; ++q)
            ov[q] = f2bf(w00 * e0[q] + w01 * e0[q + 1]
                       + w10 * e1[q] + w11 * e1[q + 1]);
        *reinterpret_cast<ushort8*>(ip + tid * 8) = ov;
    }
}

// ---------------------------------------------------------------------------
// FUSED BN stats + softplus spatial sums (att half), 1024 threads,
// wave-per-batch, plane kept in registers between phases.
// ---------------------------------------------------------------------------
__global__ __launch_bounds__(1024) void attstats_k(const ushort* __restrict__ dp,
                                                   const float* __restrict__ gamma,
                                                   const float* __restrict__ beta,
                                                   float* __restrict__ scale,
                                                   float* __restrict__ shift,
                                                   float* __restrict__ rsum) {
    const int c = blockIdx.x;
    const int t = threadIdx.x;
    const int wv = t >> 6, lane = t & 63;
    const ushort* p = dp + ((size_t)wv * 1024 + 512 + c) * HWS;

    ushort8 v[8];
    float s = 0.f, s2 = 0.f;
#pragma unroll
    for (int k = 0; k < 8; ++k) {
        v[k] = *reinterpret_cast<const ushort8*>(p + lane * 8 + k * 512);
#pragma unroll
        for (int j = 0; j < 8; ++j) { float f = bf2f(v[k][j]); s += f; s2 += f * f; }
    }
#pragma unroll
    for (int off = 32; off > 0; off >>= 1) {
        s += __shfl_down(s, off, 64);
        s2 += __shfl_down(s2, off, 64);
    }
    __shared__ float t1[16], t2[16], scsh[2];
    if (lane == 0) { t1[wv] = s; t2[wv] = s2; }
    __syncthreads();
    if (t == 0) {
        float S = 0.f, S2 = 0.f;
#pragma unroll
        for (int k = 0; k < 16; ++k) { S += t1[k]; S2 += t2[k]; }
        float n = (float)(NB * HWS);
        float mean = S / n;
        float var = S2 / n - mean * mean;
        float invs = rsqrtf(var + BN_EPS);
        float sc = invs * gamma[c];
        float sh = beta[c] - mean * sc;
        scale[c] = sc; shift[c] = sh;
        scsh[0] = sc; scsh[1] = sh;
    }
    __syncthreads();
    float sc = scsh[0], sh = scsh[1];
    float ps = 0.f;
#pragma unroll
    for (int k = 0; k < 8; ++k)
#pragma unroll
        for (int j = 0; j < 8; ++j)
            ps += softplus_fast(bf2f(v[k][j]) * sc + sh);
#pragma unroll
    for (int off = 32; off > 0; off >>= 1) ps += __shfl_down(ps, off, 64);
    if (lane == 0) rsum[wv * DPC + c] = 1.f / ps;
}

// ---------------------------------------------------------------------------
// m = softplus(bn(att)) * rsum * disp, transposed via LDS -> mT[b][hw][512]
// ---------------------------------------------------------------------------
__global__ __launch_bounds__(256) void attmulT_k(const ushort* __restrict__ dp,
                                                 const float* __restrict__ scale,
                                                 const float* __restrict__ shift,
                                                 const float* __restrict__ rsum,
                                                 ushort* __restrict__ mT) {
    const int b = blockIdx.z, c0 = blockIdx.y * 64, hw0 = blockIdx.x * 64;
    __shared__ float tile[64][65];
    const int tid = threadIdx.x;
#pragma unroll
    for (int r = 0; r < 16; ++r) {
        int cl = r * 4 + (tid >> 6), hwl = tid & 63;
        int c = c0 + cl;
        size_t aidx = ((size_t)b * 1024 + 512 + c) * HWS + hw0 + hwl;
        size_t didx = ((size_t)b * 1024 + c) * HWS + hw0 + hwl;
        float a = bf2f(dp[aidx]) * scale[c] + shift[c];
        float m = softplus_fast(a) * rsum[b * DPC + c] * bf2f(dp[didx]);
        tile[cl][hwl] = m;
    }
    __syncthreads();
#pragma unroll
    for (int r = 0; r < 16; ++r) {
        int hwl = r * 4 + (tid >> 6), cl = tid & 63;
        mT[((size_t)b * HWS + hw0 + hwl) * DPC + c0 + cl] = f2bf(tile[cl][hwl]);
    }
}

// ---------------------------------------------------------------------------
// Reduce GEMM2 partials -> final BN scale/shift (512 partials per channel)
// ---------------------------------------------------------------------------
__global__ __launch_bounds__(256) void bnred_k(const float* __restrict__ part_s,
                                               const float* __restrict__ part_s2,
                                               const float* __restrict__ gamma,
                                               const float* __restrict__ beta,
                                               float* __restrict__ scale,
                                               float* __restrict__ shift) {
    const int c = blockIdx.x, t = threadIdx.x;
    float s  = part_s[(size_t)c * 512 + t]  + part_s[(size_t)c * 512 + 256 + t];
    float s2 = part_s2[(size_t)c * 512 + t] + part_s2[(size_t)c * 512 + 256 + t];
#pragma unroll
    for (int off = 32; off > 0; off >>= 1) {
        s += __shfl_down(s, off, 64);
        s2 += __shfl_down(s2, off, 64);
    }
    __shared__ float t1[4], t2[4];
    int lane = t & 63, wid = t >> 6;
    if (lane == 0) { t1[wid] = s; t2[wid] = s2; }
    __syncthreads();
    if (t == 0) {
        float S = t1[0] + t1[1] + t1[2] + t1[3];
        float S2 = t2[0] + t2[1] + t2[2] + t2[3];
        float n = (float)(NB * HWS);
        float mean = S / n;
        float var = S2 / n - mean * mean;
        float invs = rsqrtf(var + BN_EPS);
        float sc = invs * gamma[c];
        scale[c] = sc;
        shift[c] = beta[c] - mean * sc;
    }
}

// Final: out = relu(t*scale + shift), t bf16 -> out f32
__global__ __launch_bounds__(256) void final_k(const ushort* __restrict__ t,
                                               const float* __restrict__ scale,
                                               const float* __restrict__ shift,
                                               float* __restrict__ out) {
    int i = (blockIdx.x * 256 + threadIdx.x) * 8;
    int c = (i >> 12) & (COUTC - 1);
    float sc = scale[c], sh = shift[c];
    ushort8 v = *reinterpret_cast<const ushort8*>(t + i);
    float4 a, b4;
#pragma unroll
    for (int j = 0; j < 4; ++j) a[j] = fmaxf(bf2f(v[j]) * sc + sh, 0.f);
#pragma unroll
    for (int j = 0; j < 4; ++j) b4[j] = fmaxf(bf2f(v[4 + j]) * sc + sh, 0.f);
    *reinterpret_cast<float4*>(out + i) = a;
    *reinterpret_cast<float4*>(out + i + 4) = b4;
}

extern "C" void kernel_launch(void* const* d_in, const int* in_sizes, int n_in,
                              void* d_out, int out_size, void* d_ws, size_t ws_size,
                              hipStream_t stream) {
    const float* x           = (const float*)d_in[0];
    const float* pre_w       = (const float*)d_in[1];
    const float* pre_b       = (const float*)d_in[2];
    const float* sigma       = (const float*)d_in[3];
    const float* offsets     = (const float*)d_in[4];
    const float* atten_w     = (const float*)d_in[5];
    const float* atten_b     = (const float*)d_in[6];
    const float* atten_gamma = (const float*)d_in[7];
    const float* atten_beta  = (const float*)d_in[8];
    const float* post_w      = (const float*)d_in[9];
    const float* post_b      = (const float*)d_in[10];
    const float* bn_gamma    = (const float*)d_in[11];
    const float* bn_beta     = (const float*)d_in[12];
    float* out = (float*)d_out;

    // Workspace (MiB offsets), peak 227 MiB.
    char* wsb = (char*)d_ws;
    ushort* xT     = (ushort*)(wsb);
    ushort* wbig   = (ushort*)(wsb + ((size_t)32 << 20));
    ushort* wpost  = wbig + 1024 * 256;
    float*  stats  = (float*)(wsb + ((size_t)33 << 20));
    ushort* dpout  = (ushort*)(wsb + ((size_t)34 << 20));
    ushort* tbuf   = dpout;   // [34,66): dead pre half after attmulT
    ushort* mT     = (ushort*)(wsb + ((size_t)162 << 20));
    float*  part_s  = (float*)(wsb + ((size_t)226 << 20));   // 512 KiB
    float*  part_s2 = part_s + 256 * 512;                    // 512 KiB

    float* scaleA = stats;          // 512
    float* shiftA = stats + 512;    // 512
    float* rsum   = stats + 1024;   // 8192
    float* scale2 = stats + 9216;   // 256
    float* shift2 = stats + 9472;   // 256

    // 0. casts / transposes
    castT_k<<<dim3(64, 4, NB), 256, 0, stream>>>(x, xT);
    cast_k<<<128, 256, 0, stream>>>(pre_w,   wbig,             DPC * CINC);
    cast_k<<<128, 256, 0, stream>>>(atten_w, wbig + 512 * 256, DPC * CINC);
    cast_k<<<128, 256, 0, stream>>>(post_w,  wpost,            COUTC * DPC);

    // 1. FUSED pre+atten conv1x1 (MFMA, XCD-chunked swizzle) -> dpout
    mfma_gemm_k<1024, CINC, true, false, true><<<2048, 256, 0, stream>>>(
        wbig, xT, pre_b, atten_b, nullptr, dpout, nullptr, nullptr);
    // 2. fused dynamic pool + displace, in place on pre half
    pooldisp_k<<<NB * DPC, 512, 0, stream>>>(dpout, sigma, offsets);
    // 3. FUSED BN stats + softplus spatial sums (atten)
    attstats_k<<<DPC, 1024, 0, stream>>>(dpout, atten_gamma, atten_beta,
                                         scaleA, shiftA, rsum);
    // 4. attmul, transposed -> mT
    attmulT_k<<<dim3(64, 8, NB), 256, 0, stream>>>(dpout, scaleA, shiftA, rsum, mT);
    // 5. post conv1x1 (MFMA) + f32 skip -> t bf16 + partials
    mfma_gemm_k<COUTC, DPC, false, true, false><<<dim3(32, 1, NB), 256, 0, stream>>>(
        wpost, mT, post_b, post_b, x, tbuf, part_s, part_s2);
    // 6. reduce partials -> scale2/shift2
    bnred_k<<<COUTC, 256, 0, stream>>>(part_s, part_s2, bn_gamma, bn_beta,
                                       scale2, shift2);
    // 7. relu(bn(t)) -> out f32
    final_k<<<(NB * COUTC * HWS) / 2048, 256, 0, stream>>>(tbuf, scale2, shift2, out);
}

// Round 19
// 262.616 us; speedup vs baseline: 1.0270x; 1.0270x over previous
//
#include <hip/hip_runtime.h>
#include <cmath>

#define NB   16
#define CINC 256
#define DPC  512
#define COUTC 256
#define HWS  4096
#define EPSF 1.1920928955078125e-07f
#define BN_EPS 1e-5f
#define EXP_CLAMP 88.722835f
#define TS 76   // pooldisp tmp f32 stride
#define PS2 66  // pooldisp pl ushort stride

typedef unsigned int uint32;
typedef unsigned short ushort;
typedef __bf16 bf16x8 __attribute__((ext_vector_type(8)));
typedef float f32x4 __attribute__((ext_vector_type(4)));
typedef unsigned short ushort8 __attribute__((ext_vector_type(8)));

__device__ inline ushort f2bf(float f) {          // native RNE cvt
    __bf16 h = (__bf16)f;
    return __builtin_bit_cast(ushort, h);
}
__device__ inline float bf2f(ushort u) {
    return __builtin_bit_cast(float, (uint32)u << 16);
}
__device__ inline float softplus_fast(float v) {
    return fmaxf(v, 0.f) + __logf(1.f + __expf(-fabsf(v)));
}
__device__ __forceinline__ void gload16(const void* g, void* l) {
    __builtin_amdgcn_global_load_lds(
        (__attribute__((address_space(1))) void*)g,
        (__attribute__((address_space(3))) void*)l, 16, 0, 0);
}
// raw barrier fenced against ALL instruction motion
__device__ __forceinline__ void hard_barrier() {
    __builtin_amdgcn_sched_barrier(0);
    __builtin_amdgcn_s_barrier();
    __builtin_amdgcn_sched_barrier(0);
}

// ---------------------------------------------------------------------------
// MFMA bf16 GEMM, 256(M)x128(N) tile, 4 waves of 128x64 = (8,4) frag grid.
// 2-slab counted-vmcnt pipeline: vmcnt(6) waits current slab; refill after
// the 2nd fenced barrier.  Conflict-free LDS via source-side slot
// permutation (slot ^= (row>>1)&3).  (Round-16 configuration: best measured.)
// out[b][o][hw] = bias[o] + sum_k A[o][k] * BT[b][hw][k]
// DUALBIAS: bias split at o=512.  PARTIALS: add f32 skip, write bf16 t, and
// emit per-channel (sum, sumsq) partials.  grid (HWS/128, OTOT/256, NB).
// ---------------------------------------------------------------------------
template<int OTOT, int KTOT, bool DUALBIAS, bool PARTIALS>
__global__ __launch_bounds__(256) void mfma_gemm_k(
    const ushort* __restrict__ A, const ushort* __restrict__ BT,
    const float* __restrict__ bias1, const float* __restrict__ bias2,
    const float* __restrict__ skip, ushort* __restrict__ outp,
    float* __restrict__ part_s, float* __restrict__ part_s2) {
    const int hw0 = blockIdx.x * 128;
    const int o0  = blockIdx.y * 256;
    const int b   = blockIdx.z;
    __shared__ ushort As[2][256 * 32];   // 32 KB
    __shared__ ushort Bs[2][128 * 32];   // 16 KB
    const int tid  = threadIdx.x;
    const int lane = tid & 63;
    const int w    = tid >> 6;
    const int wm0  = (w >> 1) * 128;     // o-half
    const int wn0  = (w & 1) * 64;       // hw-half

    f32x4 acc[8][4] = {};

    const ushort* Ab = A + (size_t)o0 * KTOT;
    const ushort* Bb = BT + ((size_t)b * HWS + hw0) * KTOT;
    const int rsub  = lane >> 2;
    const int ksubp = ((lane & 3) ^ ((lane >> 3) & 3)) * 8;

    auto stage = [&](int buf, int k0) {   // 6 global_load_lds per thread
#pragma unroll
        for (int i = 0; i < 4; ++i) {     // A: wave w covers rows w*64 .. +63
            const int row = w * 64 + i * 16 + rsub;
            gload16(Ab + (size_t)row * KTOT + k0 + ksubp, &As[buf][(w * 64 + i * 16) * 32]);
        }
#pragma unroll
        for (int i = 0; i < 2; ++i) {     // B: wave w covers rows w*32 .. +31
            const int row = w * 32 + i * 16 + rsub;
            gload16(Bb + (size_t)row * KTOT + k0 + ksubp, &Bs[buf][(w * 32 + i * 16) * 32]);
        }
    };

    constexpr int NSTEP = KTOT / 32;
    stage(0, 0);
    stage(1, 32);
    int cur = 0;
    for (int step = 0; step < NSTEP; ++step) {
        // wait for current slab only; next slab's 6 loads stay in flight
        if (step == NSTEP - 1) asm volatile("s_waitcnt vmcnt(0)" ::: "memory");
        else                   asm volatile("s_waitcnt vmcnt(6)" ::: "memory");
        hard_barrier();                      // all waves' current slab landed
        bf16x8 af[8], bfr[4];
#pragma unroll
        for (int mi = 0; mi < 8; ++mi) {
            int row = wm0 + mi * 16 + (lane & 15);
            int sl = (lane >> 4) ^ ((row >> 1) & 3);
            af[mi] = *reinterpret_cast<const bf16x8*>(&As[cur][row * 32 + sl * 8]);
        }
#pragma unroll
        for (int ni = 0; ni < 4; ++ni) {
            int row = wn0 + ni * 16 + (lane & 15);
            int sl = (lane >> 4) ^ ((row >> 1) & 3);
            bfr[ni] = *reinterpret_cast<const bf16x8*>(&Bs[cur][row * 32 + sl * 8]);
        }
#pragma unroll
        for (int mi = 0; mi < 8; ++mi)
#pragma unroll
            for (int ni = 0; ni < 4; ++ni)
                acc[mi][ni] = __builtin_amdgcn_mfma_f32_16x16x32_bf16(
                    af[mi], bfr[ni], acc[mi][ni], 0, 0, 0);
        hard_barrier();                      // all waves done READING cur
        if (step + 2 < NSTEP) stage(cur, (step + 2) * 32);   // refill cur
        cur ^= 1;
    }

    // reuse dead staging LDS for partial-sum exchange
    float* pS  = reinterpret_cast<float*>(&As[0][0]);   // [2][256]
    float* pS2 = pS + 512;
    if constexpr (PARTIALS) __syncthreads();   // staging drained (vmcnt 0)

    // D frag: col = lane&15 (hw), row = (lane>>4)*4 + r (o).
#pragma unroll
    for (int mi = 0; mi < 8; ++mi) {
#pragma unroll
        for (int r = 0; r < 4; ++r) {
            int chL = wm0 + mi * 16 + ((lane >> 4) << 2) + r;
            int o = o0 + chL;
            float bi;
            if constexpr (DUALBIAS) bi = (o < 512) ? bias1[o] : bias2[o - 512];
            else bi = bias1[o];
            size_t base = ((size_t)b * OTOT + o) * HWS + hw0 + wn0 + (lane & 15);
            float s1 = 0.f, s2 = 0.f;
#pragma unroll
            for (int ni = 0; ni < 4; ++ni) {
                float v = acc[mi][ni][r] + bi;
                if constexpr (PARTIALS) v += skip[base + ni * 16];
                ushort tb = f2bf(v);
                outp[base + ni * 16] = tb;
                if constexpr (PARTIALS) {
                    float vf = bf2f(tb);
                    s1 += vf; s2 += vf * vf;
                }
            }
            if constexpr (PARTIALS) {
#pragma unroll
                for (int off = 1; off <= 8; off <<= 1) {
                    s1 += __shfl_xor(s1, off, 64);
                    s2 += __shfl_xor(s2, off, 64);
                }
                if ((lane & 15) == 0) {
                    pS[(w & 1) * 256 + chL]  = s1;
                    pS2[(w & 1) * 256 + chL] = s2;
                }
            }
        }
    }
    if constexpr (PARTIALS) {
        __syncthreads();
        if (tid < 256) {
            int k = blockIdx.x * NB + b;   // 0..511
            float S  = pS[tid]  + pS[256 + tid];
            float S2 = pS2[tid] + pS2[256 + tid];
            part_s[(size_t)(o0 + tid) * 512 + k]  = S;
            part_s2[(size_t)(o0 + tid) * 512 + k] = S2;
        }
    }
}

// ---------------------------------------------------------------------------
// x [B][256][HW] f32  ->  xT [B][HW][256] bf16
// ---------------------------------------------------------------------------
__global__ __launch_bounds__(256) void castT_k(const float* __restrict__ x,
                                               ushort* __restrict__ xT) {
    const int b = blockIdx.z, c0 = blockIdx.y * 64, hw0 = blockIdx.x * 64;
    __shared__ float tile[64][65];
    const int tid = threadIdx.x;
#pragma unroll
    for (int r = 0; r < 16; ++r) {
        int cl = r * 4 + (tid >> 6), hwl = tid & 63;
        tile[cl][hwl] = x[((size_t)b * CINC + c0 + cl) * HWS + hw0 + hwl];
    }
    __syncthreads();
#pragma unroll
    for (int r = 0; r < 16; ++r) {
        int hwl = r * 4 + (tid >> 6), cl = tid & 63;
        xT[((size_t)b * HWS + hw0 + hwl) * CINC + c0 + cl] = f2bf(tile[cl][hwl]);
    }
}

// generic f32 -> bf16 cast
__global__ __launch_bounds__(256) void cast_k(const float* __restrict__ in,
                                              ushort* __restrict__ out, int n) {
    int i = (blockIdx.x * 256 + threadIdx.x) * 4;
    if (i < n) {
        float4 v = *reinterpret_cast<const float4*>(in + i);
        out[i + 0] = f2bf(v.x); out[i + 1] = f2bf(v.y);
        out[i + 2] = f2bf(v.z); out[i + 3] = f2bf(v.w);
    }
}

// ---------------------------------------------------------------------------
// FUSED dynamic_pool + displace v4: 512 threads, exp+row-pass fused -> tmp
// f32; col-pass+log -> pl bf16 (stride 66); displace with 9-tap reuse.
// IN PLACE on plane (b,c) of dpout[b][1024][hw], c < 512.
// ---------------------------------------------------------------------------
__global__ __launch_bounds__(512, 8) void pooldisp_k(ushort* __restrict__ dp,
                                                     const float* __restrict__ sigma,
                                                     const float* __restrict__ offsets) {
    const int bc = blockIdx.x;
    const int b = bc >> 9, c = bc & 511;
    __shared__ float  tmp[68 * TS];
    __shared__ ushort pl[64 * PS2];
    const int tid = threadIdx.x;
    ushort* ip = dp + ((size_t)b * 1024 + c) * HWS;

    float s = sigma[c];
    float inv = 0.5f / (s * s + EPSF);
    float g0 = __expf(-4.f * inv), g1 = __expf(-1.f * inv);
    float gs = g0 + g1 + 1.f + g1 + g0;
    float rnorm = 1.f / (gs * gs);

    {
        int r4 = tid >> 7, col = tid & 127;
        if (col < TS) {
            int row = (r4 < 2) ? r4 : 64 + r4;   // 0,1,66,67
            tmp[row * TS + col] = 0.f;
        }
    }
    {
        int hr = tid >> 3, w0 = (tid & 7) * 8;
        const ushort* rp = ip + hr * 64 + w0;
        ushort8 mv = *reinterpret_cast<const ushort8*>(rp);
        float e[12];
        e[0] = (w0 > 0) ? __expf(fminf(bf2f(rp[-2]), EXP_CLAMP)) : 0.f;
        e[1] = (w0 > 0) ? __expf(fminf(bf2f(rp[-1]), EXP_CLAMP)) : 0.f;
#pragma unroll
        for (int q = 0; q < 8; ++q)
            e[2 + q] = __expf(fminf(bf2f(mv[q]), EXP_CLAMP));
        e[10] = (w0 < 56) ? __expf(fminf(bf2f(rp[8]), EXP_CLAMP)) : 0.f;
        e[11] = (w0 < 56) ? __expf(fminf(bf2f(rp[9]), EXP_CLAMP)) : 0.f;
        f32x4 o0, o1;
#pragma unroll
        for (int j = 0; j < 4; ++j) {
            o0[j] = g0 * (e[j] + e[j + 4]) + g1 * (e[j + 1] + e[j + 3]) + e[j + 2];
            o1[j] = g0 * (e[j + 4] + e[j + 8]) + g1 * (e[j + 5] + e[j + 7]) + e[j + 6];
        }
        *reinterpret_cast<f32x4*>(&tmp[(hr + 2) * TS + w0]) = o0;
        *reinterpret_cast<f32x4*>(&tmp[(hr + 2) * TS + w0 + 4]) = o1;
    }
    __syncthreads();

#pragma unroll
    for (int t = 0; t < 2; ++t) {
        int task = tid + t * 512;
        int h = task >> 4, wq = (task & 15) * 4;
        f32x4 t0 = *reinterpret_cast<const f32x4*>(&tmp[(h + 0) * TS + wq]);
        f32x4 t1 = *reinterpret_cast<const f32x4*>(&tmp[(h + 1) * TS + wq]);
        f32x4 t2 = *reinterpret_cast<const f32x4*>(&tmp[(h + 2) * TS + wq]);
        f32x4 t3 = *reinterpret_cast<const f32x4*>(&tmp[(h + 3) * TS + wq]);
        f32x4 t4 = *reinterpret_cast<const f32x4*>(&tmp[(h + 4) * TS + wq]);
        ushort o[4];
#pragma unroll
        for (int j = 0; j < 4; ++j) {
            float v = g0 * (t0[j] + t4[j]) + g1 * (t1[j] + t3[j]) + t2[j];
            o[j] = f2bf(__logf(v * rnorm + EPSF));
        }
        *reinterpret_cast<uint32*>(&pl[h * PS2 + wq]) =
            (uint32)o[0] | ((uint32)o[1] << 16);
        *reinterpret_cast<uint32*>(&pl[h * PS2 + wq + 2]) =
            (uint32)o[2] | ((uint32)o[3] << 16);
    }
    __syncthreads();

    {
        int oi = c >> 3;
        float dy = offsets[oi * 2 + 0];
        float dx = offsets[oi * 2 + 1];
        float y0f = floorf(dy), x0f = floorf(dx);
        float fy = dy - y0f, fx = dx - x0f;
        int y0 = (int)y0f, x0 = (int)x0f;
        float w00 = (1.f - fy) * (1.f - fx), w01 = (1.f - fy) * fx;
        float w10 = fy * (1.f - fx),         w11 = fy * fx;
        int h = tid >> 3, w = (tid & 7) * 8;
        int ry0 = h + y0, ry1 = ry0 + 1;
        bool my0 = (ry0 >= 0) & (ry0 < 64);
        bool my1 = (ry1 >= 0) & (ry1 < 64);
        float e0[9], e1[9];
#pragma unroll
        for (int j = 0; j < 9; ++j) {
            int col = w + x0 + j;
            bool mx = (col >= 0) & (col < 64);
            e0[j] = (my0 & mx) ? bf2f(pl[ry0 * PS2 + col]) : 0.f;
            e1[j] = (my1 & mx) ? bf2f(pl[ry1 * PS2 + col]) : 0.f;
        }
        ushort8 ov;
#pragma unroll
        for (int q = 0; q < 8; ++q)
            ov[q] = f2bf(w00 * e0[q] + w01 * e0[q + 1]
                       + w10 * e1[q] + w11 * e1[q + 1]);
        *reinterpret_cast<ushort8*>(ip + tid * 8) = ov;
    }
}

// ---------------------------------------------------------------------------
// FUSED BN stats + softplus spatial sums (att half), 1024 threads,
// wave-per-batch, plane kept in registers between phases.
// ---------------------------------------------------------------------------
__global__ __launch_bounds__(1024) void attstats_k(const ushort* __restrict__ dp,
                                                   const float* __restrict__ gamma,
                                                   const float* __restrict__ beta,
                                                   float* __restrict__ scale,
                                                   float* __restrict__ shift,
                                                   float* __restrict__ rsum) {
    const int c = blockIdx.x;
    const int t = threadIdx.x;
    const int wv = t >> 6, lane = t & 63;
    const ushort* p = dp + ((size_t)wv * 1024 + 512 + c) * HWS;

    ushort8 v[8];
    float s = 0.f, s2 = 0.f;
#pragma unroll
    for (int k = 0; k < 8; ++k) {
        v[k] = *reinterpret_cast<const ushort8*>(p + lane * 8 + k * 512);
#pragma unroll
        for (int j = 0; j < 8; ++j) { float f = bf2f(v[k][j]); s += f; s2 += f * f; }
    }
#pragma unroll
    for (int off = 32; off > 0; off >>= 1) {
        s += __shfl_down(s, off, 64);
        s2 += __shfl_down(s2, off, 64);
    }
    __shared__ float t1[16], t2[16], scsh[2];
    if (lane == 0) { t1[wv] = s; t2[wv] = s2; }
    __syncthreads();
    if (t == 0) {
        float S = 0.f, S2 = 0.f;
#pragma unroll
        for (int k = 0; k < 16; ++k) { S += t1[k]; S2 += t2[k]; }
        float n = (float)(NB * HWS);
        float mean = S / n;
        float var = S2 / n - mean * mean;
        float invs = rsqrtf(var + BN_EPS);
        float sc = invs * gamma[c];
        float sh = beta[c] - mean * sc;
        scale[c] = sc; shift[c] = sh;
        scsh[0] = sc; scsh[1] = sh;
    }
    __syncthreads();
    float sc = scsh[0], sh = scsh[1];
    float ps = 0.f;
#pragma unroll
    for (int k = 0; k < 8; ++k)
#pragma unroll
        for (int j = 0; j < 8; ++j)
            ps += softplus_fast(bf2f(v[k][j]) * sc + sh);
#pragma unroll
    for (int off = 32; off > 0; off >>= 1) ps += __shfl_down(ps, off, 64);
    if (lane == 0) rsum[wv * DPC + c] = 1.f / ps;
}

// ---------------------------------------------------------------------------
// m = softplus(bn(att)) * rsum * disp, transposed via LDS -> mT[b][hw][512].
// v2: vectorized ushort8 fill (64c x 64hw tile; task = (cl, 8hw-group)),
// bank-check: (cl + 8*hg + j) mod 32 -> each bank 2x = free.
// ---------------------------------------------------------------------------
__global__ __launch_bounds__(256) void attmulT_k(const ushort* __restrict__ dp,
                                                 const float* __restrict__ scale,
                                                 const float* __restrict__ shift,
                                                 const float* __restrict__ rsum,
                                                 ushort* __restrict__ mT) {
    const int b = blockIdx.z, c0 = blockIdx.y * 64, hw0 = blockIdx.x * 64;
    __shared__ float tile[64][65];
    const int tid = threadIdx.x;
#pragma unroll
    for (int t = 0; t < 2; ++t) {
        int task = tid + t * 256;
        int cl = task >> 3, hg = (task & 7) * 8;
        int c = c0 + cl;
        float sc = scale[c], sh = shift[c], rs = rsum[b * DPC + c];
        size_t aoff = ((size_t)b * 1024 + 512 + c) * HWS + hw0 + hg;
        size_t doff = ((size_t)b * 1024 + c) * HWS + hw0 + hg;
        ushort8 av = *reinterpret_cast<const ushort8*>(dp + aoff);
        ushort8 dv = *reinterpret_cast<const ushort8*>(dp + doff);
        float* tr = &tile[cl][hg];
#pragma unroll
        for (int j = 0; j < 8; ++j) {
            float a = bf2f(av[j]) * sc + sh;
            tr[j] = softplus_fast(a) * rs * bf2f(dv[j]);
        }
    }
    __syncthreads();
#pragma unroll
    for (int r = 0; r < 16; ++r) {
        int hwl = r * 4 + (tid >> 6), cl = tid & 63;
        mT[((size_t)b * HWS + hw0 + hwl) * DPC + c0 + cl] = f2bf(tile[cl][hwl]);
    }
}

// ---------------------------------------------------------------------------
// Reduce GEMM2 partials -> final BN scale/shift (512 partials per channel)
// ---------------------------------------------------------------------------
__global__ __launch_bounds__(256) void bnred_k(const float* __restrict__ part_s,
                                               const float* __restrict__ part_s2,
                                               const float* __restrict__ gamma,
                                               const float* __restrict__ beta,
                                               float* __restrict__ scale,
                                               float* __restrict__ shift) {
    const int c = blockIdx.x, t = threadIdx.x;
    float s  = part_s[(size_t)c * 512 + t]  + part_s[(size_t)c * 512 + 256 + t];
    float s2 = part_s2[(size_t)c * 512 + t] + part_s2[(size_t)c * 512 + 256 + t];
#pragma unroll
    for (int off = 32; off > 0; off >>= 1) {
        s += __shfl_down(s, off, 64);
        s2 += __shfl_down(s2, off, 64);
    }
    __shared__ float t1[4], t2[4];
    int lane = t & 63, wid = t >> 6;
    if (lane == 0) { t1[wid] = s; t2[wid] = s2; }
    __syncthreads();
    if (t == 0) {
        float S = t1[0] + t1[1] + t1[2] + t1[3];
        float S2 = t2[0] + t2[1] + t2[2] + t2[3];
        float n = (float)(NB * HWS);
        float mean = S / n;
        float var = S2 / n - mean * mean;
        float invs = rsqrtf(var + BN_EPS);
        float sc = invs * gamma[c];
        scale[c] = sc;
        shift[c] = beta[c] - mean * sc;
    }
}

// Final: out = relu(t*scale + shift), t bf16 -> out f32
__global__ __launch_bounds__(256) void final_k(const ushort* __restrict__ t,
                                               const float* __restrict__ scale,
                                               const float* __restrict__ shift,
                                               float* __restrict__ out) {
    int i = (blockIdx.x * 256 + threadIdx.x) * 8;
    int c = (i >> 12) & (COUTC - 1);
    float sc = scale[c], sh = shift[c];
    ushort8 v = *reinterpret_cast<const ushort8*>(t + i);
    float4 a, b4;
#pragma unroll
    for (int j = 0; j < 4; ++j) a[j] = fmaxf(bf2f(v[j]) * sc + sh, 0.f);
#pragma unroll
    for (int j = 0; j < 4; ++j) b4[j] = fmaxf(bf2f(v[4 + j]) * sc + sh, 0.f);
    *reinterpret_cast<float4*>(out + i) = a;
    *reinterpret_cast<float4*>(out + i + 4) = b4;
}

extern "C" void kernel_launch(void* const* d_in, const int* in_sizes, int n_in,
                              void* d_out, int out_size, void* d_ws, size_t ws_size,
                              hipStream_t stream) {
    const float* x           = (const float*)d_in[0];
    const float* pre_w       = (const float*)d_in[1];
    const float* pre_b       = (const float*)d_in[2];
    const float* sigma       = (const float*)d_in[3];
    const float* offsets     = (const float*)d_in[4];
    const float* atten_w     = (const float*)d_in[5];
    const float* atten_b     = (const float*)d_in[6];
    const float* atten_gamma = (const float*)d_in[7];
    const float* atten_beta  = (const float*)d_in[8];
    const float* post_w      = (const float*)d_in[9];
    const float* post_b      = (const float*)d_in[10];
    const float* bn_gamma    = (const float*)d_in[11];
    const float* bn_beta     = (const float*)d_in[12];
    float* out = (float*)d_out;

    // Workspace (MiB offsets), peak 227 MiB.
    char* wsb = (char*)d_ws;
    ushort* xT     = (ushort*)(wsb);
    ushort* wbig   = (ushort*)(wsb + ((size_t)32 << 20));
    ushort* wpost  = wbig + 1024 * 256;
    float*  stats  = (float*)(wsb + ((size_t)33 << 20));
    ushort* dpout  = (ushort*)(wsb + ((size_t)34 << 20));
    ushort* tbuf   = dpout;   // [34,66): dead pre half after attmulT
    ushort* mT     = (ushort*)(wsb + ((size_t)162 << 20));
    float*  part_s  = (float*)(wsb + ((size_t)226 << 20));   // 512 KiB
    float*  part_s2 = part_s + 256 * 512;                    // 512 KiB

    float* scaleA = stats;          // 512
    float* shiftA = stats + 512;    // 512
    float* rsum   = stats + 1024;   // 8192
    float* scale2 = stats + 9216;   // 256
    float* shift2 = stats + 9472;   // 256

    // 0. casts / transposes
    castT_k<<<dim3(64, 4, NB), 256, 0, stream>>>(x, xT);
    cast_k<<<128, 256, 0, stream>>>(pre_w,   wbig,             DPC * CINC);
    cast_k<<<128, 256, 0, stream>>>(atten_w, wbig + 512 * 256, DPC * CINC);
    cast_k<<<128, 256, 0, stream>>>(post_w,  wpost,            COUTC * DPC);

    // 1. FUSED pre+atten conv1x1 (MFMA, 256x128 tile) -> dpout
    mfma_gemm_k<1024, CINC, true, false><<<dim3(32, 4, NB), 256, 0, stream>>>(
        wbig, xT, pre_b, atten_b, nullptr, dpout, nullptr, nullptr);
    // 2. fused dynamic pool + displace, in place on pre half
    pooldisp_k<<<NB * DPC, 512, 0, stream>>>(dpout, sigma, offsets);
    // 3. FUSED BN stats + softplus spatial sums (atten)
    attstats_k<<<DPC, 1024, 0, stream>>>(dpout, atten_gamma, atten_beta,
                                         scaleA, shiftA, rsum);
    // 4. attmul v2 (vectorized fill), transposed -> mT
    attmulT_k<<<dim3(64, 8, NB), 256, 0, stream>>>(dpout, scaleA, shiftA, rsum, mT);
    // 5. post conv1x1 (MFMA) + f32 skip -> t bf16 + partials
    mfma_gemm_k<COUTC, DPC, false, true><<<dim3(32, 1, NB), 256, 0, stream>>>(
        wpost, mT, post_b, post_b, x, tbuf, part_s, part_s2);
    // 6. reduce partials -> scale2/shift2
    bnred_k<<<COUTC, 256, 0, stream>>>(part_s, part_s2, bn_gamma, bn_beta,
                                       scale2, shift2);
    // 7. relu(bn(t)) -> out f32
    final_k<<<(NB * COUTC * HWS) / 2048, 256, 0, stream>>>(tbuf, scale2, shift2, out);
}